// Round 14
// baseline (467.917 us; speedup 1.0000x reference)
//
#include <hip/hip_runtime.h>

// BasalGanglia fused kernel (MI355X / gfx950).
// R18 = R17 pipeline at BM=16 / grid 512: TWO resident blocks per CU with
// FULL register-resident weights (no streaming — R12's fatal flaw).
// RF audit: 2 blocks x 512thr x ~120 VGPR x 4B = 491KB <= 512KB CU register
// file, so each block holds its own Ws copy. LDS was the real 2-block blocker
// (92KB > 160/2): BM 16 -> ~65KB => LDS and VGPR both admit 2 blocks/CU.
// Two async blocks fill each other's barrier/latency dead time (the overlap
// R6/R7/R13 could not get inside one barrier-locked block).
// Keeps: R15 2-segment pipeline (A||C||G then B||D), R17 GST=84 + lstmc hoist,
// acc-carry 2*xstn, permuted whh, (512,2) no-spill tier.
// Gates: occupancy ~45-50% + dur ~240-270 if residency works; VGPR<=124 &
// WRITE ~672KB (spill gate).

typedef _Float16 f16_t;
typedef _Float16 f16x8 __attribute__((ext_vector_type(8)));
typedef _Float16 f16x4 __attribute__((ext_vector_type(4)));
typedef float floatx4 __attribute__((ext_vector_type(4)));
typedef float floatx2 __attribute__((ext_vector_type(2)));

#define BTOT 8192
#define BM   16
#define NTHR 512
#define NBLK (BTOT / BM)   // 512 blocks -> 2 per CU
#define VSTR 328   // f16 stride; dword-stride 164 -> 4-way aliasing (min for 16B align)
#define XST  32    // xgpe/hxf row stride (f16), k-pad zeroed
#define GST  84    // gates row stride (dwords); 84%32=20 -> 8-bank spread

struct Params {
  const float *stimulus, *deltavf, *hx0, *cx0;
  const float *w_vf0, *b_vf0, *w_vf1, *b_vf1, *w_vf2, *b_vf2, *w_vf3, *b_vf3;
  const float *w_jd1, *b_jd1, *w_jd2, *b_jd2, *w_kd1, *b_kd1, *w_kd2, *b_kd2;
  const float *w_sg, *b_sg, *w_gs, *b_gs, *w_glat, *b_glat, *w_slat, *b_slat;
  const float *w_d1gpi, *b_d1gpi, *w_stngpi, *b_stngpi;
  const float *w_ih, *b_ih, *w_hh, *b_hh;
  float* out;
};

struct __align__(16) Smem {
  f16_t vstn[BM * VSTR];        // 10496 B
  f16_t xgpe[2][BM * XST];      // 2048 (double buffer)
  f16_t hxf[BM * XST];          // 1024
  f16_t wB2[21 * 512];          // 21504: t<19 gs-frag, t=19/20 glat-frag
  f16_t wsp[10 * 512];          // 10240: stngpi frags
  f16_t whh[5 * 512];           // 5120: w_hh gate frags (row-permuted: r'=4j+g)
  union { float h1f[BM * 128]; float scr[1600]; float gates[BM * GST]; } u; // 8192
  float h0f[BM * 64];           // 4096
  float V_D2f[BM * 20];         // 1280
  float lstmc[20][12];          // 960: [j][bihh(4) | wih0(4) | wih1(4)]
  float bsumS[304];             // b_slat+b_gs, pad->0
  float bsg[20];                // b_sg+b_glat
  float DPs[BM * 2], vgpis[BM * 2], lamS[BM];
};                              // ~65 KB -> 2 blocks/CU

__device__ __forceinline__ float rcp_f(float x) { return __builtin_amdgcn_rcpf(x); }
__device__ __forceinline__ float sigm_fast(float x) { return rcp_f(1.f + __expf(-x)); }
__device__ __forceinline__ float tanh_fast(float x) { return 1.f - 2.f * rcp_f(1.f + __expf(2.f * x)); }

// 8 f32 weights row[k0..k0+7] -> f16x8, zero for k>=kmax or !valid (4-granular).
__device__ __forceinline__ f16x8 ldfrag(const float* row, int k0, int kmax, bool valid) {
  float4 z = make_float4(0.f, 0.f, 0.f, 0.f);
  int nv = valid ? (kmax - k0) : 0;
  float4 f0 = (nv >= 4) ? *(const float4*)(row + k0) : z;
  float4 f1 = (nv >= 8) ? *(const float4*)(row + k0 + 4) : z;
  f16x8 r;
  r[0] = (f16_t)f0.x; r[1] = (f16_t)f0.y; r[2] = (f16_t)f0.z; r[3] = (f16_t)f0.w;
  r[4] = (f16_t)f1.x; r[5] = (f16_t)f1.y; r[6] = (f16_t)f1.z; r[7] = (f16_t)f1.w;
  return r;
}

__global__ __launch_bounds__(NTHR, 2) void bg_main(Params P) {
  __shared__ Smem S;
  const int tid  = threadIdx.x;
  const int lane = tid & 63;
  const int wv   = tid >> 6;
  const int q    = lane >> 4;
  const int cl   = lane & 15;
  const int row0 = blockIdx.x * BM;
  const floatx4 zf = {0.f, 0.f, 0.f, 0.f};

  // ================= init + LDS weight-frag staging =================
  if (tid < BM) S.lamS[tid] = sigm_fast(P.deltavf[row0 + tid]);
  for (int i = tid; i < BM * 2; i += NTHR) S.vgpis[i] = 0.f;
  for (int i = tid; i < 2 * BM * XST; i += NTHR) ((f16_t*)S.xgpe)[i] = (f16_t)0.f;
  for (int i = tid; i < BM * XST; i += NTHR) {
    int m = i >> 5, j = i & 31;
    S.hxf[i] = (j < 20) ? (f16_t)P.hx0[(size_t)(row0 + m) * 20 + j] : (f16_t)0.f;
  }
  for (int i = tid; i < BM * VSTR; i += NTHR) S.vstn[i] = (f16_t)0.f;
  for (int i = tid; i < 21 * 512; i += NTHR) {        // gs / glat frags
    int t = i >> 9, l = (i >> 3) & 63, jj = i & 7;
    int c2 = l & 15, k = ((l >> 4) << 3) + jj;
    float v = 0.f;
    if (t < 19) { int n = t * 16 + c2; if (n < 300 && k < 20) v = P.w_gs[n * 20 + k]; }
    else        { int g = (t - 19) * 16 + c2; if (g < 20 && k < 20) v = P.w_glat[g * 20 + k]; }
    S.wB2[i] = (f16_t)v;
  }
  for (int i = tid; i < 10 * 512; i += NTHR) {        // stngpi frags
    int c = i >> 9, l = (i >> 3) & 63, jj = i & 7;
    int p = l & 15, k = c * 32 + ((l >> 4) << 3) + jj;
    float v = (p < 2 && k < 300) ? P.w_stngpi[p * 300 + k] : 0.f;
    S.wsp[i] = (f16_t)v;
  }
  for (int i = tid; i < 5 * 512; i += NTHR) {         // w_hh gate frags, PERMUTED
    int t = i >> 9, l = (i >> 3) & 63, jj = i & 7;
    int c2 = l & 15, k = ((l >> 4) << 3) + jj;
    int orig = (c2 & 3) * 20 + 4 * t + (c2 >> 2);     // r'=4j+g -> orig g*20+j
    S.whh[i] = (f16_t)((k < 20) ? P.w_hh[orig * 20 + k] : 0.f);
  }
  for (int i = tid; i < 240; i += NTHR) {             // LSTM consts [j][12]
    int j = i / 12, c = i - j * 12;
    float v;
    if (c < 4)      v = P.b_ih[c * 20 + j] + P.b_hh[c * 20 + j];
    else if (c < 8) v = P.w_ih[((c - 4) * 20 + j) * 2 + 0];
    else            v = P.w_ih[((c - 8) * 20 + j) * 2 + 1];
    S.lstmc[j][c] = v;
  }
  for (int i = tid; i < 304; i += NTHR) S.bsumS[i] = (i < 300) ? (P.b_slat[i] + P.b_gs[i]) : 0.f;
  for (int i = tid; i < 20; i += NTHR)  S.bsg[i] = P.b_sg[i] + P.b_glat[i];

  { // h0 = relu(stim @ w_vf0^T + b): 16 rows x 64 out; 2 rows/thread
    int o = tid & 63, mb = (tid >> 6) * 2;
    const float4* wr = (const float4*)(P.w_vf0 + o * 300);
    float bias = P.b_vf0[o], a[2];
    a[0] = bias; a[1] = bias;
    for (int kq = 0; kq < 75; ++kq) {
      float4 w = wr[kq];
#pragma unroll
      for (int u = 0; u < 2; ++u) {
        float4 v = *(const float4*)(P.stimulus + (size_t)(row0 + mb + u) * 300 + kq * 4);
        a[u] = fmaf(v.x, w.x, a[u]); a[u] = fmaf(v.y, w.y, a[u]);
        a[u] = fmaf(v.z, w.z, a[u]); a[u] = fmaf(v.w, w.w, a[u]);
      }
    }
#pragma unroll
    for (int u = 0; u < 2; ++u) S.h0f[(mb + u) * 64 + o] = fmaxf(a[u], 0.f);
  }
  __syncthreads();
  { // h1: 16 x 128; 4 rows/thread
    int o = tid & 127, mb = (tid >> 7) * 4;
    const float* wr = P.w_vf1 + o * 64;
    float bias = P.b_vf1[o], a[4];
#pragma unroll
    for (int u = 0; u < 4; ++u) a[u] = bias;
    for (int k = 0; k < 64; ++k) {
      float w = wr[k];
#pragma unroll
      for (int u = 0; u < 4; ++u) a[u] = fmaf(S.h0f[(mb + u) * 64 + k], w, a[u]);
    }
#pragma unroll
    for (int u = 0; u < 4; ++u) S.u.h1f[(mb + u) * 128 + o] = fmaxf(a[u], 0.f);
  }
  __syncthreads();
  { // h2 -> h0f: 16 x 64; 2 rows/thread
    int o = tid & 63, mb = (tid >> 6) * 2;
    const float* wr = P.w_vf2 + o * 128;
    float bias = P.b_vf2[o], a[2];
    a[0] = bias; a[1] = bias;
    for (int k = 0; k < 128; ++k) {
      float w = wr[k];
#pragma unroll
      for (int u = 0; u < 2; ++u) a[u] = fmaf(S.u.h1f[(mb + u) * 128 + k], w, a[u]);
    }
#pragma unroll
    for (int u = 0; u < 2; ++u) S.h0f[(mb + u) * 64 + o] = fmaxf(a[u], 0.f);
  }
  __syncthreads();
  { // drives -> scr[0:1280); vt output
    int oid = tid & 127, mb = (tid >> 7) * 4;
    if (oid < 80) {
      int which = oid / 20, o = oid - which * 20;
      const float *wp, *bp;
      if (which == 0)      { wp = P.w_jd1; bp = P.b_jd1; }
      else if (which == 1) { wp = P.w_jd2; bp = P.b_jd2; }
      else if (which == 2) { wp = P.w_kd1; bp = P.b_kd1; }
      else                 { wp = P.w_kd2; bp = P.b_kd2; }
      float bias = bp[o], a[4];
#pragma unroll
      for (int u = 0; u < 4; ++u) a[u] = bias;
      for (int kq = 0; kq < 75; ++kq) {
        float4 w = *(const float4*)(wp + o * 300 + kq * 4);
#pragma unroll
        for (int u = 0; u < 4; ++u) {
          float4 v = *(const float4*)(P.stimulus + (size_t)(row0 + mb + u) * 300 + kq * 4);
          a[u] = fmaf(v.x, w.x, a[u]); a[u] = fmaf(v.y, w.y, a[u]);
          a[u] = fmaf(v.z, w.z, a[u]); a[u] = fmaf(v.w, w.w, a[u]);
        }
      }
#pragma unroll
      for (int u = 0; u < 4; ++u) S.u.scr[which * 320 + (mb + u) * 20 + o] = a[u];
    }
    if (tid < BM) {
      float a = P.b_vf3[0];
      for (int k = 0; k < 64; ++k) a = fmaf(S.h0f[tid * 64 + k], P.w_vf3[k], a);
      P.out[(size_t)BTOT * 20 + row0 + tid] = tanh_fast(a);
    }
  }
  __syncthreads();
  for (int i = tid; i < BM * 20; i += NTHR) { // FF -> V_D1 scr[1280:), V_D2f
    int m = i / 20;
    float j1 = S.u.scr[i],       j2 = S.u.scr[320 + i];
    float k1 = S.u.scr[640 + i], k2 = S.u.scr[960 + i];
    float L = S.lamS[m], v1 = 0.f, v2 = 0.f;
    for (int s = 0; s < 20; ++s) {
      v1 = sigm_fast(L * (j1 * (1.f - v1) + (1.f - k1) * v1));
      v2 = sigm_fast(L * (j2 * (1.f - v2) + (1.f - k2) * v2));
    }
    S.u.scr[1280 + i] = v1;
    S.V_D2f[i] = v2;
  }
  __syncthreads();
  if (tid < BM * 2) { // V_GPi_DP
    int m = tid >> 1, p2 = tid & 1;
    float a = P.b_d1gpi[p2];
    for (int o = 0; o < 20; ++o) a = fmaf(S.u.scr[1280 + m * 20 + o], P.w_d1gpi[p2 * 20 + o], a);
    S.DPs[tid] = a;
  }
  __syncthreads();

  // ================= register-resident slat/sg A-frags (R6/R9 map) ==========
  // slot j: tile t = wv + 8*j; t<19 slat, t=19/20 sg (waves 3,4), t>=21 dead.
  f16x8 Ws[3][10];
#pragma unroll
  for (int j = 0; j < 3; ++j) {
    int t = wv + 8 * j;
    if (t < 19) {
      int n = t * 16 + cl;
#pragma unroll
      for (int c = 0; c < 10; ++c)
        Ws[j][c] = ldfrag(P.w_slat + (size_t)(n < 300 ? n : 0) * 300, c * 32 + q * 8, 300, n < 300);
    } else if (t < 21) {
      int g = (t - 19) * 16 + cl;
#pragma unroll
      for (int c = 0; c < 10; ++c)
        Ws[j][c] = ldfrag(P.w_sg + (size_t)(g < 20 ? g : 0) * 300, c * 32 + q * 8, 300, g < 20);
    } else {
      f16x8 z;
#pragma unroll
      for (int e = 0; e < 8; ++e) z[e] = (f16_t)0.f;
#pragma unroll
      for (int c = 0; c < 10; ++c) Ws[j][c] = z;
    }
  }
  const float lamB = S.lamS[cl];
  const float bstn0 = P.b_stngpi[0], bstn1 = P.b_stngpi[1];
  // LSTM thread-owned state: tid<320 owns elem (m0, j0)
  const bool lown = (tid < BM * 20);
  const int  m0 = lown ? tid / 20 : 0;
  const int  j0 = tid - m0 * 20;
  float cxr0 = lown ? P.cx0[(size_t)(row0 + m0) * 20 + j0] : 0.f;
  float hxr0 = 0.f;
  // hoisted LSTM constants (12 regs)
  const floatx4 cb0 = *(const floatx4*)&S.lstmc[j0][0];
  const floatx4 wA0 = *(const floatx4*)&S.lstmc[j0][4];
  const floatx4 wB0 = *(const floatx4*)&S.lstmc[j0][8];
  const bool isSgW = (wv == 3 || wv == 4);

  // acc carries 2*xstn across iterations (slat slots); starts at 0.
  floatx4 acc[3];
  acc[0] = zf; acc[1] = zf; acc[2] = zf;

  // ============ STN recurrence: 51 pipelined groups, 2 barriers each ========
  // Seg even: A(g) || C(g-1) wave5 || G(g-1) waves 6,7
  // Seg odd : B(g) || D(g-1)
  for (int g = 0; g <= 50; ++g) {
    const bool run = (g < 50), ran = (g > 0);
    const int po = g & 1, pn = po ^ 1;

    // ---------------- Seg even ----------------
    if (run) {
      if (isSgW) acc[2] = zf;   // sg slot fresh
      __builtin_amdgcn_s_setprio(1);
#pragma unroll
      for (int c = 0; c < 10; ++c) {
        f16x8 b0 = *(const f16x8*)&S.vstn[cl * VSTR + c * 32 + q * 8];
#pragma unroll
        for (int j = 0; j < 3; ++j) {
          if (wv + 8 * j < 21)
            acc[j] = __builtin_amdgcn_mfma_f32_16x16x32_f16(Ws[j][c], b0, acc[j], 0, 0, 0);
        }
      }
      __builtin_amdgcn_s_setprio(0);
      if (isSgW) {
        f16x8 Wg = *(const f16x8*)&S.wB2[(wv + 16) * 512 + lane * 8];
        f16x8 g0 = *(const f16x8*)&S.xgpe[po][cl * XST + q * 8];
        acc[2] = __builtin_amdgcn_mfma_f32_16x16x32_f16(Wg, g0, acc[2], 0, 0, 0);
        int g0i = (wv - 3) * 16 + q * 4;
        if (g0i < 20) {
          floatx4 bg4 = *(const floatx4*)&S.bsg[g0i];
          floatx4 vd4 = *(const floatx4*)&S.V_D2f[cl * 20 + g0i];
          f16x4 pk;
#pragma unroll
          for (int r = 0; r < 4; ++r) pk[r] = (f16_t)(acc[2][r] + bg4[r] - vd4[r]);
          *(f16x4*)&S.xgpe[pn][cl * XST + g0i] = pk;
        }
      }
    }
    if (ran && wv == 5) { // C(g-1): stngpi on vstn(g-1) -> vgpi(g-1)
      floatx4 ip0 = zf;
#pragma unroll
      for (int c = 0; c < 10; ++c) {
        f16x8 Wp = *(const f16x8*)&S.wsp[c * 512 + lane * 8];
        f16x8 b0 = *(const f16x8*)&S.vstn[cl * VSTR + c * 32 + q * 8];
        ip0 = __builtin_amdgcn_mfma_f32_16x16x32_f16(Wp, b0, ip0, 0, 0, 0);
      }
      if (q == 0) {
        floatx2 vg = *(const floatx2*)&S.vgpis[cl * 2];
        floatx2 dp = *(const floatx2*)&S.DPs[cl * 2];
        float ipa = lamB * (ip0[0] + bstn0);
        float ipb = lamB * (ip0[1] + bstn1);
        vg[0] = vg[0] + 0.1f * (-vg[0] - dp[0] + 2.f * ipa);
        vg[1] = vg[1] + 0.1f * (-vg[1] - dp[1] + 2.f * ipb);
        *(floatx2*)&S.vgpis[cl * 2] = vg;
      }
    }
    if (ran && (wv == 6 || wv == 7)) { // G(g-1): hh-gates from hxf(g-2)
      int tb = (wv == 6) ? 0 : 3;
      int tc = (wv == 6) ? 3 : 2;
      for (int tt = 0; tt < tc; ++tt) {
        int t = tb + tt;
        f16x8 Wh = *(const f16x8*)&S.whh[t * 512 + lane * 8];
        f16x8 h0 = *(const f16x8*)&S.hxf[cl * XST + q * 8];
        floatx4 gA = __builtin_amdgcn_mfma_f32_16x16x32_f16(Wh, h0, zf, 0, 0, 0);
        *(floatx4*)&S.u.gates[cl * GST + t * 16 + q * 4] = gA;
      }
    }
    __syncthreads(); // end Seg even: xgpe_new, vgpis(g-1), gates(g-1) ready

    // ---------------- Seg odd ----------------
    if (run) { // B(g): acc += gs @ xgpe_new; xstn/vstn update
      f16x8 x0 = *(const f16x8*)&S.xgpe[pn][cl * XST + q * 8];
#pragma unroll
      for (int j = 0; j < 3; ++j) {
        int t = wv + 8 * j;
        if (t < 19) {
          f16x8 Wg = *(const f16x8*)&S.wB2[t * 512 + lane * 8];
          acc[j] = __builtin_amdgcn_mfma_f32_16x16x32_f16(Wg, x0, acc[j], 0, 0, 0);
        }
      }
#pragma unroll
      for (int j = 0; j < 3; ++j) {
        int t = wv + 8 * j;
        if (t < 19) {
          int n0 = t * 16 + q * 4;
          if (!(t == 18 && q == 3)) {  // n0..n0+3 all < 300
            floatx4 bs4 = *(const floatx4*)&S.bsumS[n0];
            f16x4 pk;
#pragma unroll
            for (int r = 0; r < 4; ++r) {
              float tmp = acc[j][r] + bs4[r];      // = 2*xo + W.v + bs
              float xn  = tmp * (1.0f / 3.0f);     // new xstn
              acc[j][r] = tmp * (2.0f / 3.0f);     // carry 2*xn
              pk[r] = (f16_t)tanh_fast(lamB * xn);
            }
            *(f16x4*)&S.vstn[cl * VSTR + n0] = pk;
          }
        }
      }
    }
    if (ran && lown) { // D(g-1): LSTM pointwise from gates(g-1)/vgpis(g-1)
      floatx4 g4 = *(const floatx4*)&S.u.gates[m0 * GST + j0 * 4];
      floatx2 vg = *(const floatx2*)&S.vgpis[m0 * 2];
      float gi = g4[0] + cb0[0] - wA0[0] * vg[0] - wB0[0] * vg[1];
      float gf = g4[1] + cb0[1] - wA0[1] * vg[0] - wB0[1] * vg[1];
      float gg = g4[2] + cb0[2] - wA0[2] * vg[0] - wB0[2] * vg[1];
      float go = g4[3] + cb0[3] - wA0[3] * vg[0] - wB0[3] * vg[1];
      float cn = sigm_fast(gf) * cxr0 + sigm_fast(gi) * tanh_fast(gg);
      cxr0 = cn;
      hxr0 = sigm_fast(go) * tanh_fast(cn);
      S.hxf[m0 * XST + j0] = (f16_t)hxr0;
    }
    __syncthreads(); // end Seg odd: vstn(g), hxf(g-1) ready
  }

  // ---- output hx from registers (D(49) ran at g=50) ----
  if (lown) P.out[(size_t)(row0 + m0) * 20 + j0] = hxr0;
}

extern "C" void kernel_launch(void* const* d_in, const int* in_sizes, int n_in,
                              void* d_out, int out_size, void* d_ws, size_t ws_size,
                              hipStream_t stream) {
  (void)in_sizes; (void)n_in; (void)out_size; (void)d_ws; (void)ws_size;
  Params P;
  P.stimulus = (const float*)d_in[0];
  P.deltavf  = (const float*)d_in[1];
  P.hx0 = (const float*)d_in[2];
  P.cx0 = (const float*)d_in[3];
  P.w_vf0 = (const float*)d_in[4];  P.b_vf0 = (const float*)d_in[5];
  P.w_vf1 = (const float*)d_in[6];  P.b_vf1 = (const float*)d_in[7];
  P.w_vf2 = (const float*)d_in[8];  P.b_vf2 = (const float*)d_in[9];
  P.w_vf3 = (const float*)d_in[10]; P.b_vf3 = (const float*)d_in[11];
  P.w_jd1 = (const float*)d_in[12]; P.b_jd1 = (const float*)d_in[13];
  P.w_jd2 = (const float*)d_in[14]; P.b_jd2 = (const float*)d_in[15];
  P.w_kd1 = (const float*)d_in[16]; P.b_kd1 = (const float*)d_in[17];
  P.w_kd2 = (const float*)d_in[18]; P.b_kd2 = (const float*)d_in[19];
  P.w_sg  = (const float*)d_in[20]; P.b_sg  = (const float*)d_in[21];
  P.w_gs  = (const float*)d_in[22]; P.b_gs  = (const float*)d_in[23];
  P.w_glat= (const float*)d_in[24]; P.b_glat= (const float*)d_in[25];
  P.w_slat= (const float*)d_in[26]; P.b_slat= (const float*)d_in[27];
  P.w_d1gpi  = (const float*)d_in[28]; P.b_d1gpi  = (const float*)d_in[29];
  P.w_stngpi = (const float*)d_in[30]; P.b_stngpi = (const float*)d_in[31];
  P.w_ih = (const float*)d_in[32]; P.b_ih = (const float*)d_in[33];
  P.w_hh = (const float*)d_in[34]; P.b_hh = (const float*)d_in[35];
  P.out  = (float*)d_out;
  bg_main<<<NBLK, NTHR, 0, stream>>>(P);
}

// Round 15
// 387.376 us; speedup vs baseline: 1.2079x; 1.2079x over previous
//
#include <hip/hip_runtime.h>

// BasalGanglia fused kernel (MI355X / gfx950).
// R19 = R17 (304us, VGPR 120, no spill) with XST 32 -> 40.
// Evidence: R18 killed the 2-block branch (residency only at 64-reg tier;
// occupancy stuck 23.5%, dur 380). Remaining counter signal: bank conflicts
// 1.41e7 ~= 1100cy/iter/CU. Audit: xgpe/hxf at XST=32 f16 = 16-dword stride
// -> lanes cl, cl+2 collide (16*2 % 32 == 0) -> 8-way conflict on every b128
// read of xgpe (A g0/g1, B x0/x1) and hxf (G h0/h1), ~30 reads/iter at 2.94x.
// XST=40 (20 dwords): cl pairs with cl+8 only -> 2-way (free, m136); rows stay
// 16B-aligned (80B). Single-variable change vs R17.
// Keeps: R15 2-segment pipeline (A||C||G, B||D), GST=84, lstmc hoist,
// acc-carry 2*xstn, permuted whh, (512,2) no-spill tier.

typedef _Float16 f16_t;
typedef _Float16 f16x8 __attribute__((ext_vector_type(8)));
typedef _Float16 f16x4 __attribute__((ext_vector_type(4)));
typedef float floatx4 __attribute__((ext_vector_type(4)));
typedef float floatx2 __attribute__((ext_vector_type(2)));

#define BTOT 8192
#define BM   32
#define NTHR 512
#define NBLK 256
#define VSTR 328   // f16 stride; dword-stride 164 -> 2-way (free) bank aliasing
#define XST  40    // xgpe/hxf row stride (f16); 20 dwords -> 2-way (was 16 -> 8-way)
#define GST  84    // gates row stride (dwords); 84%32=20 -> 8-bank spread

struct Params {
  const float *stimulus, *deltavf, *hx0, *cx0;
  const float *w_vf0, *b_vf0, *w_vf1, *b_vf1, *w_vf2, *b_vf2, *w_vf3, *b_vf3;
  const float *w_jd1, *b_jd1, *w_jd2, *b_jd2, *w_kd1, *b_kd1, *w_kd2, *b_kd2;
  const float *w_sg, *b_sg, *w_gs, *b_gs, *w_glat, *b_glat, *w_slat, *b_slat;
  const float *w_d1gpi, *b_d1gpi, *w_stngpi, *b_stngpi;
  const float *w_ih, *b_ih, *w_hh, *b_hh;
  float* out;
};

struct __align__(16) Smem {
  f16_t vstn[BM * VSTR];        // 20992 B
  f16_t xgpe[2][BM * XST];      // 5120 (double buffer)
  f16_t hxf[BM * XST];          // 2560
  f16_t wB2[21 * 512];          // 21504: t<19 gs-frag, t=19/20 glat-frag
  f16_t wsp[10 * 512];          // 10240: stngpi frags
  f16_t whh[5 * 512];           // 5120: w_hh gate frags (row-permuted: r'=4j+g)
  union { float h1f[BM * 128]; float scr[3200]; float gates[BM * GST]; } u; // 16384
  float h0f[BM * 64];           // 8192
  float V_D2f[BM * 20];         // 2560
  float lstmc[20][12];          // 960: [j][bihh(4) | wih0(4) | wih1(4)]
  float bsumS[304];             // b_slat+b_gs, pad->0
  float bsg[20];                // b_sg+b_glat
  float DPs[BM * 2], vgpis[BM * 2], lamS[BM];
};                              // ~96 KB -> 1 block/CU

__device__ __forceinline__ float rcp_f(float x) { return __builtin_amdgcn_rcpf(x); }
__device__ __forceinline__ float sigm_fast(float x) { return rcp_f(1.f + __expf(-x)); }
__device__ __forceinline__ float tanh_fast(float x) { return 1.f - 2.f * rcp_f(1.f + __expf(2.f * x)); }

// 8 f32 weights row[k0..k0+7] -> f16x8, zero for k>=kmax or !valid (4-granular).
__device__ __forceinline__ f16x8 ldfrag(const float* row, int k0, int kmax, bool valid) {
  float4 z = make_float4(0.f, 0.f, 0.f, 0.f);
  int nv = valid ? (kmax - k0) : 0;
  float4 f0 = (nv >= 4) ? *(const float4*)(row + k0) : z;
  float4 f1 = (nv >= 8) ? *(const float4*)(row + k0 + 4) : z;
  f16x8 r;
  r[0] = (f16_t)f0.x; r[1] = (f16_t)f0.y; r[2] = (f16_t)f0.z; r[3] = (f16_t)f0.w;
  r[4] = (f16_t)f1.x; r[5] = (f16_t)f1.y; r[6] = (f16_t)f1.z; r[7] = (f16_t)f1.w;
  return r;
}

__global__ __launch_bounds__(NTHR, 2) void bg_main(Params P) {
  __shared__ Smem S;
  const int tid  = threadIdx.x;
  const int lane = tid & 63;
  const int wv   = tid >> 6;
  const int q    = lane >> 4;
  const int cl   = lane & 15;
  const int row0 = blockIdx.x * BM;
  const floatx4 zf = {0.f, 0.f, 0.f, 0.f};

  // ================= init + LDS weight-frag staging =================
  if (tid < BM) S.lamS[tid] = sigm_fast(P.deltavf[row0 + tid]);
  for (int i = tid; i < BM * 2; i += NTHR) S.vgpis[i] = 0.f;
  for (int i = tid; i < 2 * BM * XST; i += NTHR) ((f16_t*)S.xgpe)[i] = (f16_t)0.f;
  for (int i = tid; i < BM * XST; i += NTHR) {
    int m = i / XST, j = i - m * XST;
    S.hxf[i] = (j < 20) ? (f16_t)P.hx0[row0 * 20 + m * 20 + j] : (f16_t)0.f;
  }
  for (int i = tid; i < BM * VSTR; i += NTHR) S.vstn[i] = (f16_t)0.f;
  for (int i = tid; i < 21 * 512; i += NTHR) {        // gs / glat frags
    int t = i >> 9, l = (i >> 3) & 63, jj = i & 7;
    int c2 = l & 15, k = ((l >> 4) << 3) + jj;
    float v = 0.f;
    if (t < 19) { int n = t * 16 + c2; if (n < 300 && k < 20) v = P.w_gs[n * 20 + k]; }
    else        { int g = (t - 19) * 16 + c2; if (g < 20 && k < 20) v = P.w_glat[g * 20 + k]; }
    S.wB2[i] = (f16_t)v;
  }
  for (int i = tid; i < 10 * 512; i += NTHR) {        // stngpi frags
    int c = i >> 9, l = (i >> 3) & 63, jj = i & 7;
    int p = l & 15, k = c * 32 + ((l >> 4) << 3) + jj;
    float v = (p < 2 && k < 300) ? P.w_stngpi[p * 300 + k] : 0.f;
    S.wsp[i] = (f16_t)v;
  }
  for (int i = tid; i < 5 * 512; i += NTHR) {         // w_hh gate frags, PERMUTED
    int t = i >> 9, l = (i >> 3) & 63, jj = i & 7;
    int c2 = l & 15, k = ((l >> 4) << 3) + jj;
    // tile-row c2 -> permuted gate-row r' = 16t+c2 = 4j+g -> orig row g*20+j
    int orig = (c2 & 3) * 20 + 4 * t + (c2 >> 2);
    S.whh[i] = (f16_t)((k < 20) ? P.w_hh[orig * 20 + k] : 0.f);
  }
  for (int i = tid; i < 240; i += NTHR) {             // LSTM consts [j][12]
    int j = i / 12, c = i - j * 12;
    float v;
    if (c < 4)      v = P.b_ih[c * 20 + j] + P.b_hh[c * 20 + j];
    else if (c < 8) v = P.w_ih[((c - 4) * 20 + j) * 2 + 0];
    else            v = P.w_ih[((c - 8) * 20 + j) * 2 + 1];
    S.lstmc[j][c] = v;
  }
  for (int i = tid; i < 304; i += NTHR) S.bsumS[i] = (i < 300) ? (P.b_slat[i] + P.b_gs[i]) : 0.f;
  for (int i = tid; i < 20; i += NTHR)  S.bsg[i] = P.b_sg[i] + P.b_glat[i];

  { // h0 = relu(stim @ w_vf0^T + b)
    int o = tid & 63, mb = (tid >> 6) * 4;
    const float4* wr = (const float4*)(P.w_vf0 + o * 300);
    float bias = P.b_vf0[o], a[4];
#pragma unroll
    for (int u = 0; u < 4; ++u) a[u] = bias;
    for (int kq = 0; kq < 75; ++kq) {
      float4 w = wr[kq];
#pragma unroll
      for (int u = 0; u < 4; ++u) {
        float4 v = *(const float4*)(P.stimulus + (size_t)(row0 + mb + u) * 300 + kq * 4);
        a[u] = fmaf(v.x, w.x, a[u]); a[u] = fmaf(v.y, w.y, a[u]);
        a[u] = fmaf(v.z, w.z, a[u]); a[u] = fmaf(v.w, w.w, a[u]);
      }
    }
#pragma unroll
    for (int u = 0; u < 4; ++u) S.h0f[(mb + u) * 64 + o] = fmaxf(a[u], 0.f);
  }
  __syncthreads();
  { // h1
    int o = tid & 127, mb = (tid >> 7) * 8;
    const float* wr = P.w_vf1 + o * 64;
    float bias = P.b_vf1[o], a[8];
#pragma unroll
    for (int u = 0; u < 8; ++u) a[u] = bias;
    for (int k = 0; k < 64; ++k) {
      float w = wr[k];
#pragma unroll
      for (int u = 0; u < 8; ++u) a[u] = fmaf(S.h0f[(mb + u) * 64 + k], w, a[u]);
    }
#pragma unroll
    for (int u = 0; u < 8; ++u) S.u.h1f[(mb + u) * 128 + o] = fmaxf(a[u], 0.f);
  }
  __syncthreads();
  { // h2 -> h0f
    int o = tid & 63, mb = (tid >> 6) * 4;
    const float* wr = P.w_vf2 + o * 128;
    float bias = P.b_vf2[o], a[4];
#pragma unroll
    for (int u = 0; u < 4; ++u) a[u] = bias;
    for (int k = 0; k < 128; ++k) {
      float w = wr[k];
#pragma unroll
      for (int u = 0; u < 4; ++u) a[u] = fmaf(S.u.h1f[(mb + u) * 128 + k], w, a[u]);
    }
#pragma unroll
    for (int u = 0; u < 4; ++u) S.h0f[(mb + u) * 64 + o] = fmaxf(a[u], 0.f);
  }
  __syncthreads();
  { // drives -> scr[0:2560); vt output
    int oid = tid & 127, mb = (tid >> 7) * 8;
    if (oid < 80) {
      int which = oid / 20, o = oid - which * 20;
      const float *wp, *bp;
      if (which == 0)      { wp = P.w_jd1; bp = P.b_jd1; }
      else if (which == 1) { wp = P.w_jd2; bp = P.b_jd2; }
      else if (which == 2) { wp = P.w_kd1; bp = P.b_kd1; }
      else                 { wp = P.w_kd2; bp = P.b_kd2; }
      float bias = bp[o], a[8];
#pragma unroll
      for (int u = 0; u < 8; ++u) a[u] = bias;
      for (int kq = 0; kq < 75; ++kq) {
        float4 w = *(const float4*)(wp + o * 300 + kq * 4);
#pragma unroll
        for (int u = 0; u < 8; ++u) {
          float4 v = *(const float4*)(P.stimulus + (size_t)(row0 + mb + u) * 300 + kq * 4);
          a[u] = fmaf(v.x, w.x, a[u]); a[u] = fmaf(v.y, w.y, a[u]);
          a[u] = fmaf(v.z, w.z, a[u]); a[u] = fmaf(v.w, w.w, a[u]);
        }
      }
#pragma unroll
      for (int u = 0; u < 8; ++u) S.u.scr[which * 640 + (mb + u) * 20 + o] = a[u];
    }
    if (tid < BM) {
      float a = P.b_vf3[0];
      for (int k = 0; k < 64; ++k) a = fmaf(S.h0f[tid * 64 + k], P.w_vf3[k], a);
      P.out[(size_t)BTOT * 20 + row0 + tid] = tanh_fast(a);
    }
  }
  __syncthreads();
  for (int i = tid; i < BM * 20; i += NTHR) { // FF -> V_D1 scr[2560:), V_D2f
    int m = i / 20;
    float j1 = S.u.scr[i],        j2 = S.u.scr[640 + i];
    float k1 = S.u.scr[1280 + i], k2 = S.u.scr[1920 + i];
    float L = S.lamS[m], v1 = 0.f, v2 = 0.f;
    for (int s = 0; s < 20; ++s) {
      v1 = sigm_fast(L * (j1 * (1.f - v1) + (1.f - k1) * v1));
      v2 = sigm_fast(L * (j2 * (1.f - v2) + (1.f - k2) * v2));
    }
    S.u.scr[2560 + i] = v1;
    S.V_D2f[i] = v2;
  }
  __syncthreads();
  if (tid < BM * 2) { // V_GPi_DP
    int m = tid >> 1, p2 = tid & 1;
    float a = P.b_d1gpi[p2];
    for (int o = 0; o < 20; ++o) a = fmaf(S.u.scr[2560 + m * 20 + o], P.w_d1gpi[p2 * 20 + o], a);
    S.DPs[tid] = a;
  }
  __syncthreads();

  // ================= register-resident slat/sg A-frags (R6/R9 map) ==========
  // slot j: tile t = wv + 8*j; t<19 slat, t=19/20 sg (waves 3,4), t>=21 dead.
  f16x8 Ws[3][10];
#pragma unroll
  for (int j = 0; j < 3; ++j) {
    int t = wv + 8 * j;
    if (t < 19) {
      int n = t * 16 + cl;
#pragma unroll
      for (int c = 0; c < 10; ++c)
        Ws[j][c] = ldfrag(P.w_slat + (size_t)(n < 300 ? n : 0) * 300, c * 32 + q * 8, 300, n < 300);
    } else if (t < 21) {
      int g = (t - 19) * 16 + cl;
#pragma unroll
      for (int c = 0; c < 10; ++c)
        Ws[j][c] = ldfrag(P.w_sg + (size_t)(g < 20 ? g : 0) * 300, c * 32 + q * 8, 300, g < 20);
    } else {
      f16x8 z;
#pragma unroll
      for (int e = 0; e < 8; ++e) z[e] = (f16_t)0.f;
#pragma unroll
      for (int c = 0; c < 10; ++c) Ws[j][c] = z;
    }
  }
  const float lam0 = S.lamS[cl], lam1 = S.lamS[cl + 16];
  const float bstn0 = P.b_stngpi[0], bstn1 = P.b_stngpi[1];
  // LSTM thread-owned state: e0 = tid (always valid), e1 = tid+512 (tid<128)
  const int e0 = tid,        m0 = e0 / 20, j0 = e0 - m0 * 20;
  const int e1 = tid + NTHR, m1 = e1 / 20, j1 = e1 - m1 * 20;
  const bool hase1 = (tid < BM * 20 - NTHR);
  float cxr0 = P.cx0[row0 * 20 + e0], hxr0 = P.hx0[row0 * 20 + e0];
  float cxr1 = hase1 ? P.cx0[row0 * 20 + e1] : 0.f;
  float hxr1 = hase1 ? P.hx0[row0 * 20 + e1] : 0.f;
  // hoisted LSTM constants for e0 (12 regs; e1 path keeps LDS reads)
  const floatx4 cb0 = *(const floatx4*)&S.lstmc[j0][0];
  const floatx4 wA0 = *(const floatx4*)&S.lstmc[j0][4];
  const floatx4 wB0 = *(const floatx4*)&S.lstmc[j0][8];
  const bool isSgW = (wv == 3 || wv == 4);

  // acc carries 2*xstn across iterations (slat slots); starts at 0.
  floatx4 acc[3][2];
#pragma unroll
  for (int j = 0; j < 3; ++j) { acc[j][0] = zf; acc[j][1] = zf; }

  // ============ STN recurrence: 51 pipelined groups, 2 barriers each ========
  // Seg even: A(g) || C(g-1) wave5 || G(g-1) waves 6,7
  // Seg odd : B(g) || D(g-1)
  for (int g = 0; g <= 50; ++g) {
    const bool run = (g < 50), ran = (g > 0);
    const int po = g & 1, pn = po ^ 1;

    // ---------------- Seg even ----------------
    if (run) {
      if (isSgW) { acc[2][0] = zf; acc[2][1] = zf; }   // sg slot fresh
      __builtin_amdgcn_s_setprio(1);
#pragma unroll
      for (int c = 0; c < 10; ++c) {
        f16x8 b0 = *(const f16x8*)&S.vstn[cl * VSTR + c * 32 + q * 8];
        f16x8 b1 = *(const f16x8*)&S.vstn[(16 + cl) * VSTR + c * 32 + q * 8];
#pragma unroll
        for (int j = 0; j < 3; ++j) {
          if (wv + 8 * j < 21) {
            acc[j][0] = __builtin_amdgcn_mfma_f32_16x16x32_f16(Ws[j][c], b0, acc[j][0], 0, 0, 0);
            acc[j][1] = __builtin_amdgcn_mfma_f32_16x16x32_f16(Ws[j][c], b1, acc[j][1], 0, 0, 0);
          }
        }
      }
      __builtin_amdgcn_s_setprio(0);
      if (isSgW) {
        f16x8 Wg = *(const f16x8*)&S.wB2[(wv + 16) * 512 + lane * 8];
        f16x8 g0 = *(const f16x8*)&S.xgpe[po][cl * XST + q * 8];
        f16x8 g1 = *(const f16x8*)&S.xgpe[po][(16 + cl) * XST + q * 8];
        acc[2][0] = __builtin_amdgcn_mfma_f32_16x16x32_f16(Wg, g0, acc[2][0], 0, 0, 0);
        acc[2][1] = __builtin_amdgcn_mfma_f32_16x16x32_f16(Wg, g1, acc[2][1], 0, 0, 0);
        int g0i = (wv - 3) * 16 + q * 4;
        if (g0i < 20) {
          floatx4 bg4 = *(const floatx4*)&S.bsg[g0i];
#pragma unroll
          for (int mf = 0; mf < 2; ++mf) {
            int batch = cl + 16 * mf;
            floatx4 vd4 = *(const floatx4*)&S.V_D2f[batch * 20 + g0i];
            f16x4 pk;
#pragma unroll
            for (int r = 0; r < 4; ++r) pk[r] = (f16_t)(acc[2][mf][r] + bg4[r] - vd4[r]);
            *(f16x4*)&S.xgpe[pn][batch * XST + g0i] = pk;
          }
        }
      }
    }
    if (ran && wv == 5) { // C(g-1): stngpi on vstn(g-1) -> vgpi(g-1)
      floatx4 ip0 = zf, ip1 = zf;
#pragma unroll
      for (int c = 0; c < 10; ++c) {
        f16x8 Wp = *(const f16x8*)&S.wsp[c * 512 + lane * 8];
        f16x8 b0 = *(const f16x8*)&S.vstn[cl * VSTR + c * 32 + q * 8];
        f16x8 b1 = *(const f16x8*)&S.vstn[(16 + cl) * VSTR + c * 32 + q * 8];
        ip0 = __builtin_amdgcn_mfma_f32_16x16x32_f16(Wp, b0, ip0, 0, 0, 0);
        ip1 = __builtin_amdgcn_mfma_f32_16x16x32_f16(Wp, b1, ip1, 0, 0, 0);
      }
      if (q == 0) {
#pragma unroll
        for (int mf = 0; mf < 2; ++mf) {
          int batch = cl + 16 * mf;
          float lm = mf ? lam1 : lam0;
          floatx2 vg = *(const floatx2*)&S.vgpis[batch * 2];
          floatx2 dp = *(const floatx2*)&S.DPs[batch * 2];
          float ipa = lm * ((mf ? ip1[0] : ip0[0]) + bstn0);
          float ipb = lm * ((mf ? ip1[1] : ip0[1]) + bstn1);
          vg[0] = vg[0] + 0.1f * (-vg[0] - dp[0] + 2.f * ipa);
          vg[1] = vg[1] + 0.1f * (-vg[1] - dp[1] + 2.f * ipb);
          *(floatx2*)&S.vgpis[batch * 2] = vg;
        }
      }
    }
    if (ran && (wv == 6 || wv == 7)) { // G(g-1): hh-gates from hxf(g-2)
      int tb = (wv == 6) ? 0 : 3;
      int tc = (wv == 6) ? 3 : 2;
      for (int tt = 0; tt < tc; ++tt) {
        int t = tb + tt;
        f16x8 Wh = *(const f16x8*)&S.whh[t * 512 + lane * 8];
        f16x8 h0 = *(const f16x8*)&S.hxf[cl * XST + q * 8];
        f16x8 h1 = *(const f16x8*)&S.hxf[(16 + cl) * XST + q * 8];
        floatx4 gA = __builtin_amdgcn_mfma_f32_16x16x32_f16(Wh, h0, zf, 0, 0, 0);
        floatx4 gB = __builtin_amdgcn_mfma_f32_16x16x32_f16(Wh, h1, zf, 0, 0, 0);
        int gb = t * 16 + q * 4;
        *(floatx4*)&S.u.gates[cl * GST + gb] = gA;
        *(floatx4*)&S.u.gates[(cl + 16) * GST + gb] = gB;
      }
    }
    __syncthreads(); // end Seg even: xgpe_new, vgpis(g-1), gates(g-1) ready

    // ---------------- Seg odd ----------------
    if (run) { // B(g): acc += gs @ xgpe_new; xstn/vstn update (no gates)
      f16x8 x0 = *(const f16x8*)&S.xgpe[pn][cl * XST + q * 8];
      f16x8 x1 = *(const f16x8*)&S.xgpe[pn][(16 + cl) * XST + q * 8];
#pragma unroll
      for (int j = 0; j < 3; ++j) {
        int t = wv + 8 * j;
        if (t < 19) {
          f16x8 Wg = *(const f16x8*)&S.wB2[t * 512 + lane * 8];
          acc[j][0] = __builtin_amdgcn_mfma_f32_16x16x32_f16(Wg, x0, acc[j][0], 0, 0, 0);
          acc[j][1] = __builtin_amdgcn_mfma_f32_16x16x32_f16(Wg, x1, acc[j][1], 0, 0, 0);
        }
      }
#pragma unroll
      for (int j = 0; j < 3; ++j) {
        int t = wv + 8 * j;
        if (t < 19) {
          int n0 = t * 16 + q * 4;
          if (!(t == 18 && q == 3)) {  // n0..n0+3 all < 300
            floatx4 bs4 = *(const floatx4*)&S.bsumS[n0];
#pragma unroll
            for (int mf = 0; mf < 2; ++mf) {
              float lm = mf ? lam1 : lam0;
              f16x4 pk;
#pragma unroll
              for (int r = 0; r < 4; ++r) {
                float tmp = acc[j][mf][r] + bs4[r];      // = 2*xo + W.v + bs
                float xn  = tmp * (1.0f / 3.0f);         // new xstn
                acc[j][mf][r] = tmp * (2.0f / 3.0f);     // carry 2*xn
                pk[r] = (f16_t)tanh_fast(lm * xn);
              }
              *(f16x4*)&S.vstn[(cl + 16 * mf) * VSTR + n0] = pk;
            }
          }
        }
      }
    }
    if (ran) { // D(g-1): LSTM pointwise from gates(g-1)/vgpis(g-1)
      {
        floatx4 g4 = *(const floatx4*)&S.u.gates[m0 * GST + j0 * 4];
        floatx2 vg = *(const floatx2*)&S.vgpis[m0 * 2];
        float gi = g4[0] + cb0[0] - wA0[0] * vg[0] - wB0[0] * vg[1];
        float gf = g4[1] + cb0[1] - wA0[1] * vg[0] - wB0[1] * vg[1];
        float gg = g4[2] + cb0[2] - wA0[2] * vg[0] - wB0[2] * vg[1];
        float go = g4[3] + cb0[3] - wA0[3] * vg[0] - wB0[3] * vg[1];
        float cn = sigm_fast(gf) * cxr0 + sigm_fast(gi) * tanh_fast(gg);
        cxr0 = cn;
        hxr0 = sigm_fast(go) * tanh_fast(cn);
        S.hxf[m0 * XST + j0] = (f16_t)hxr0;
      }
      if (hase1) {
        floatx4 g4 = *(const floatx4*)&S.u.gates[m1 * GST + j1 * 4];
        floatx4 cb = *(const floatx4*)&S.lstmc[j1][0];
        floatx4 w0 = *(const floatx4*)&S.lstmc[j1][4];
        floatx4 w1 = *(const floatx4*)&S.lstmc[j1][8];
        floatx2 vg = *(const floatx2*)&S.vgpis[m1 * 2];
        float gi = g4[0] + cb[0] - w0[0] * vg[0] - w1[0] * vg[1];
        float gf = g4[1] + cb[1] - w0[1] * vg[0] - w1[1] * vg[1];
        float gg = g4[2] + cb[2] - w0[2] * vg[0] - w1[2] * vg[1];
        float go = g4[3] + cb[3] - w0[3] * vg[0] - w1[3] * vg[1];
        float cn = sigm_fast(gf) * cxr1 + sigm_fast(gi) * tanh_fast(gg);
        cxr1 = cn;
        hxr1 = sigm_fast(go) * tanh_fast(cn);
        S.hxf[m1 * XST + j1] = (f16_t)hxr1;
      }
    }
    __syncthreads(); // end Seg odd: vstn(g), hxf(g-1) ready
  }

  // ---- output hx from registers (D(49) ran at g=50) ----
  P.out[(size_t)row0 * 20 + e0] = hxr0;
  if (hase1) P.out[(size_t)row0 * 20 + e1] = hxr1;
}

extern "C" void kernel_launch(void* const* d_in, const int* in_sizes, int n_in,
                              void* d_out, int out_size, void* d_ws, size_t ws_size,
                              hipStream_t stream) {
  (void)in_sizes; (void)n_in; (void)out_size; (void)d_ws; (void)ws_size;
  Params P;
  P.stimulus = (const float*)d_in[0];
  P.deltavf  = (const float*)d_in[1];
  P.hx0 = (const float*)d_in[2];
  P.cx0 = (const float*)d_in[3];
  P.w_vf0 = (const float*)d_in[4];  P.b_vf0 = (const float*)d_in[5];
  P.w_vf1 = (const float*)d_in[6];  P.b_vf1 = (const float*)d_in[7];
  P.w_vf2 = (const float*)d_in[8];  P.b_vf2 = (const float*)d_in[9];
  P.w_vf3 = (const float*)d_in[10]; P.b_vf3 = (const float*)d_in[11];
  P.w_jd1 = (const float*)d_in[12]; P.b_jd1 = (const float*)d_in[13];
  P.w_jd2 = (const float*)d_in[14]; P.b_jd2 = (const float*)d_in[15];
  P.w_kd1 = (const float*)d_in[16]; P.b_kd1 = (const float*)d_in[17];
  P.w_kd2 = (const float*)d_in[18]; P.b_kd2 = (const float*)d_in[19];
  P.w_sg  = (const float*)d_in[20]; P.b_sg  = (const float*)d_in[21];
  P.w_gs  = (const float*)d_in[22]; P.b_gs  = (const float*)d_in[23];
  P.w_glat= (const float*)d_in[24]; P.b_glat= (const float*)d_in[25];
  P.w_slat= (const float*)d_in[26]; P.b_slat= (const float*)d_in[27];
  P.w_d1gpi  = (const float*)d_in[28]; P.b_d1gpi  = (const float*)d_in[29];
  P.w_stngpi = (const float*)d_in[30]; P.b_stngpi = (const float*)d_in[31];
  P.w_ih = (const float*)d_in[32]; P.b_ih = (const float*)d_in[33];
  P.w_hh = (const float*)d_in[34]; P.b_hh = (const float*)d_in[35];
  P.out  = (float*)d_out;
  bg_main<<<NBLK, NTHR, 0, stream>>>(P);
}